// Round 1
// baseline (400.021 us; speedup 1.0000x reference)
//
#include <hip/hip_runtime.h>

// Performer (FAVOR+) attention, MI355X.
// B=4 N=4096 H=16 D=64 DIM=1024 M=256.
// Pipeline:
//  k_wtrans:  W[k][n] f32 -> wt[g][n][k] fp16   (B^T layout for MFMA)
//  k_omconv:  omega f32 -> fp16 (already [m][d] = B^T layout)
//  k_gemm:    qkv[row][col] = x @ [Wq|Wk|Wv]; Q,K stored fp16, V stored bf16
//  k_vtrans:  vT[bh][d][n] (bf16) for kv-stage B operand
//  k_kv:      pk = exp(k.om^T - |k|^2/2)/16 ; kv[bh][m][d] += pk^T v ; pksum
//  k_kvt:     kvt[bh][j][m] bf16: rows 0..63 = kv^T, row 64 = pksum, 65..79 = 0
//  k_out:     pq = exp(q.om^T - |q|^2/2)/16 ; out = (pq@kv) / (pq@pksum + 1e-6)

typedef _Float16 half8 __attribute__((ext_vector_type(8)));
typedef short short8 __attribute__((ext_vector_type(8)));
typedef float f32x4 __attribute__((ext_vector_type(4)));
typedef unsigned short ushort_t;
typedef unsigned int uint_t;

#define QKV_LD 3072

__device__ __forceinline__ ushort_t f2bf(float f) {
  uint_t u = __builtin_bit_cast(uint_t, f);
  u += 0x7fffu + ((u >> 16) & 1u);
  return (ushort_t)(u >> 16);
}

// ---------------- W transpose+convert: wt[g][n][k] = (f16)W_g[k][n] ----------------
__global__ void k_wtrans(const float* __restrict__ Wq, const float* __restrict__ Wk,
                         const float* __restrict__ Wv, _Float16* __restrict__ wt) {
  __shared__ float t[32][33];
  const int g = blockIdx.z;
  const float* W = (g == 0) ? Wq : ((g == 1) ? Wk : Wv);
  const int n0 = blockIdx.x * 32, k0 = blockIdx.y * 32;
  const int tx = threadIdx.x, ty = threadIdx.y;
#pragma unroll
  for (int j = 0; j < 4; ++j)
    t[ty + j * 8][tx] = W[(size_t)(k0 + ty + j * 8) * 1024 + n0 + tx];
  __syncthreads();
  _Float16* o = wt + (size_t)g * 1024 * 1024;
#pragma unroll
  for (int j = 0; j < 4; ++j)
    o[(size_t)(n0 + ty + j * 8) * 1024 + k0 + tx] = (_Float16)t[tx][ty + j * 8];
}

__global__ void k_omconv(const float* __restrict__ omega, _Float16* __restrict__ om) {
  int i = blockIdx.x * 256 + threadIdx.x;
  if (i < 16384) om[i] = (_Float16)omega[i];
}

// ---------------- QKV GEMM: 128x128 tile, fp16 MFMA, B^T input ----------------
__global__ __launch_bounds__(256) void k_gemm(const float* __restrict__ x,
                                              const _Float16* __restrict__ wt,
                                              ushort_t* __restrict__ qkv) {
  __shared__ _Float16 As[128][40];  // rows 80B: 2-way max on b128 reads
  __shared__ _Float16 Bs[128][40];
  const int row0 = blockIdx.x * 128;
  const int col0 = blockIdx.y * 128;
  const int g = col0 >> 10;          // 0=Q 1=K 2=V (128 | 1024, never straddles)
  const int col0g = col0 & 1023;
  const _Float16* wtg = wt + (size_t)g * (1024 * 1024);
  const int tid = threadIdx.x;
  const int lane = tid & 63;
  const int w = tid >> 6;
  const int wr = w >> 1, wc = w & 1;
  const int l15 = lane & 15, l4 = lane >> 4;

  f32x4 acc[4][4] = {};

  for (int kt = 0; kt < 32; ++kt) {
    const int k0 = kt * 32;
#pragma unroll
    for (int i = 0; i < 2; ++i) {
      int c = i * 256 + tid;
      int r = c >> 2, s = c & 3;
      const float* src = x + (size_t)(row0 + r) * 1024 + k0 + s * 8;
      float4 f0 = *(const float4*)src;
      float4 f1 = *(const float4*)(src + 4);
      half8 hh;
      hh[0] = (_Float16)f0.x; hh[1] = (_Float16)f0.y; hh[2] = (_Float16)f0.z; hh[3] = (_Float16)f0.w;
      hh[4] = (_Float16)f1.x; hh[5] = (_Float16)f1.y; hh[6] = (_Float16)f1.z; hh[7] = (_Float16)f1.w;
      *(half8*)&As[r][s * 8] = hh;
      const _Float16* bsrc = wtg + (size_t)(col0g + r) * 1024 + k0 + s * 8;
      *(half8*)&Bs[r][s * 8] = *(const half8*)bsrc;
    }
    __syncthreads();
    half8 a[4], bfr[4];
#pragma unroll
    for (int m = 0; m < 4; ++m)
      a[m] = *(const half8*)&As[wr * 64 + m * 16 + l15][l4 * 8];
#pragma unroll
    for (int n = 0; n < 4; ++n)
      bfr[n] = *(const half8*)&Bs[wc * 64 + n * 16 + l15][l4 * 8];
#pragma unroll
    for (int m = 0; m < 4; ++m)
#pragma unroll
      for (int n = 0; n < 4; ++n)
        acc[m][n] = __builtin_amdgcn_mfma_f32_16x16x32_f16(a[m], bfr[n], acc[m][n], 0, 0, 0);
    __syncthreads();
  }
  // epilogue: C row = (lane>>4)*4+reg, col = lane&15 (m89/m91-verified mapping)
#pragma unroll
  for (int m = 0; m < 4; ++m) {
    int gr0 = row0 + wr * 64 + m * 16 + l4 * 4;
#pragma unroll
    for (int n = 0; n < 4; ++n) {
      int gc = col0 + wc * 64 + n * 16 + l15;
#pragma unroll
      for (int r = 0; r < 4; ++r) {
        float v = acc[m][n][r];
        ushort_t bits = (g == 2) ? f2bf(v) : __builtin_bit_cast(ushort_t, (_Float16)v);
        qkv[(size_t)(gr0 + r) * QKV_LD + gc] = bits;
      }
    }
  }
}

// ---------------- V transpose: vT[bh][d][n] = qkv_V[b n][h*64+d] ----------------
__global__ __launch_bounds__(256) void k_vtrans(const ushort_t* __restrict__ qkv,
                                                ushort_t* __restrict__ vT) {
  __shared__ ushort_t tile[64][72];
  const int bh = blockIdx.x;
  const int nc = blockIdx.y;
  const int b = bh >> 4, h = bh & 15;
  const int n0 = nc * 64;
  const int tid = threadIdx.x;
#pragma unroll
  for (int i = 0; i < 2; ++i) {
    int c = i * 256 + tid;
    int r = c >> 3, s = c & 7;
    const ushort_t* src = qkv + (size_t)(b * 4096 + n0 + r) * QKV_LD + 2048 + h * 64 + s * 8;
    *(short8*)&tile[r][s * 8] = *(const short8*)src;
  }
  __syncthreads();
#pragma unroll
  for (int i = 0; i < 2; ++i) {
    int c = i * 256 + tid;
    int d = c >> 3, s = c & 7;
    short8 v;
#pragma unroll
    for (int j = 0; j < 8; ++j) v[j] = (short)tile[s * 8 + j][d];
    *(short8*)(vT + (size_t)(bh * 64 + d) * 4096 + n0 + s * 8) = v;
  }
}

// ---------------- fused phi(k) + kv accumulation ----------------
__global__ __launch_bounds__(256) void k_kv(const ushort_t* __restrict__ qkv,
                                            const ushort_t* __restrict__ vT,
                                            const _Float16* __restrict__ om,
                                            float* __restrict__ kv,
                                            float* __restrict__ pksum) {
  __shared__ _Float16 kt[64][72];
  __shared__ ushort_t vt[64][72];
  __shared__ ushort_t pk[256][72];  // [m][n], rows 144B
  __shared__ float nrm[64];
  const int bh = blockIdx.x, split = blockIdx.y;
  const int b = bh >> 4, h = bh & 15;
  const int tid = threadIdx.x, lane = tid & 63, w = tid >> 6;
  const int l15 = lane & 15, l4 = lane >> 4;

  // loop-invariant omega B-fragments (wave w owns m in [w*64, w*64+64))
  half8 bom[4][2];
#pragma unroll
  for (int mf = 0; mf < 4; ++mf)
#pragma unroll
    for (int ks = 0; ks < 2; ++ks)
      bom[mf][ks] = *(const half8*)(om + (size_t)(w * 64 + mf * 16 + l15) * 64 + ks * 32 + l4 * 8);

  f32x4 kvacc[4][4] = {};
  float psum[4] = {0.f, 0.f, 0.f, 0.f};

  for (int ch = 0; ch < 8; ++ch) {
    const int nbase = split * 512 + ch * 64;
#pragma unroll
    for (int i = 0; i < 2; ++i) {
      int c = i * 256 + tid;
      int r = c >> 3, s = c & 7;
      *(short8*)&kt[r][s * 8] =
          *(const short8*)(qkv + (size_t)(b * 4096 + nbase + r) * QKV_LD + 1024 + h * 64 + s * 8);
      *(short8*)&vt[r][s * 8] =
          *(const short8*)(vT + (size_t)(bh * 64 + r) * 4096 + nbase + s * 8);
    }
    __syncthreads();
    {  // row norms: 4 threads per row
      int row = tid >> 2, part = tid & 3;
      float sm = 0.f;
#pragma unroll
      for (int i = 0; i < 16; ++i) {
        float kf = (float)kt[row][part * 16 + i];
        sm += kf * kf;
      }
      sm += __shfl_xor(sm, 1);
      sm += __shfl_xor(sm, 2);
      if ((tid & 3) == 0) nrm[row] = 0.5f * sm;
    }
    __syncthreads();
    // proj (k @ om^T) -> exp -> pk (bf16, transposed to [m][n]) + psum
#pragma unroll
    for (int nf = 0; nf < 4; ++nf) {
      half8 a0 = *(const half8*)&kt[nf * 16 + l15][l4 * 8];
      half8 a1 = *(const half8*)&kt[nf * 16 + l15][32 + l4 * 8];
#pragma unroll
      for (int mf = 0; mf < 4; ++mf) {
        f32x4 f = {};
        f = __builtin_amdgcn_mfma_f32_16x16x32_f16(a0, bom[mf][0], f, 0, 0, 0);
        f = __builtin_amdgcn_mfma_f32_16x16x32_f16(a1, bom[mf][1], f, 0, 0, 0);
#pragma unroll
        for (int r = 0; r < 4; ++r) {
          int n = nf * 16 + l4 * 4 + r;
          float p = __expf(f[r] - nrm[n]) * 0.0625f;
          pk[w * 64 + mf * 16 + l15][n] = f2bf(p);
          psum[mf] += p;
        }
      }
    }
    __syncthreads();
    // kv[m][d] += pk^T v  : A = pk rows (m), B^T = vt rows (d)
#pragma unroll
    for (int ks = 0; ks < 2; ++ks) {
      short8 pa[4];
#pragma unroll
      for (int mf = 0; mf < 4; ++mf)
        pa[mf] = *(const short8*)&pk[w * 64 + mf * 16 + l15][ks * 32 + l4 * 8];
#pragma unroll
      for (int df = 0; df < 4; ++df) {
        short8 bv = *(const short8*)&vt[df * 16 + l15][ks * 32 + l4 * 8];
#pragma unroll
        for (int mf = 0; mf < 4; ++mf)
          kvacc[mf][df] = __builtin_amdgcn_mfma_f32_16x16x32_bf16(pa[mf], bv, kvacc[mf][df], 0, 0, 0);
      }
    }
    __syncthreads();
  }
#pragma unroll
  for (int mf = 0; mf < 4; ++mf)
#pragma unroll
    for (int df = 0; df < 4; ++df)
#pragma unroll
      for (int r = 0; r < 4; ++r) {
        int m = w * 64 + mf * 16 + l4 * 4 + r;
        int d = df * 16 + l15;
        atomicAdd(&kv[((size_t)bh * 256 + m) * 64 + d], kvacc[mf][df][r]);
      }
#pragma unroll
  for (int mf = 0; mf < 4; ++mf) {
    float v = psum[mf];
    v += __shfl_xor(v, 16);
    v += __shfl_xor(v, 32);
    if (lane < 16) atomicAdd(&pksum[bh * 256 + w * 64 + mf * 16 + lane], v);
  }
}

// ---------------- kv -> kvt (B^T bf16, + pksum row 64, zero pad rows) ----------------
__global__ __launch_bounds__(256) void k_kvt(const float* __restrict__ kv,
                                             const float* __restrict__ pksum,
                                             ushort_t* __restrict__ kvt) {
  const int bh = blockIdx.x, tid = threadIdx.x;
  const int d = tid >> 2, mb = (tid & 3) * 64;
  for (int j = 0; j < 64; ++j) {
    int m = mb + j;
    kvt[((size_t)bh * 80 + d) * 256 + m] = f2bf(kv[((size_t)bh * 256 + m) * 64 + d]);
  }
  kvt[((size_t)bh * 80 + 64) * 256 + tid] = f2bf(pksum[bh * 256 + tid]);
  for (int r = 65; r < 80; ++r) kvt[((size_t)bh * 80 + r) * 256 + tid] = 0;
}

// ---------------- fused phi(q) + out ----------------
__global__ __launch_bounds__(256) void k_out(const ushort_t* __restrict__ qkv,
                                             const ushort_t* __restrict__ kvt,
                                             const _Float16* __restrict__ om,
                                             float* __restrict__ outp) {
  __shared__ _Float16 qt[64][72];
  __shared__ ushort_t pq[64][264];  // [n][m], rows 528B
  __shared__ float nrm[64];
  const int bh = blockIdx.x, nc = blockIdx.y;
  const int b = bh >> 4, h = bh & 15;
  const int n0 = nc * 64;
  const int tid = threadIdx.x, lane = tid & 63, w = tid >> 6;
  const int l15 = lane & 15, l4 = lane >> 4;
#pragma unroll
  for (int i = 0; i < 2; ++i) {
    int c = i * 256 + tid;
    int r = c >> 3, s = c & 7;
    *(short8*)&qt[r][s * 8] =
        *(const short8*)(qkv + (size_t)(b * 4096 + n0 + r) * QKV_LD + h * 64 + s * 8);
  }
  __syncthreads();
  {
    int row = tid >> 2, part = tid & 3;
    float sm = 0.f;
#pragma unroll
    for (int i = 0; i < 16; ++i) {
      float qf = (float)qt[row][part * 16 + i];
      sm += qf * qf;
    }
    sm += __shfl_xor(sm, 1);
    sm += __shfl_xor(sm, 2);
    if ((tid & 3) == 0) nrm[row] = 0.5f * sm;
  }
  __syncthreads();
  // proj + exp: wave w owns rows [w*16, w*16+16)
  half8 a0 = *(const half8*)&qt[w * 16 + l15][l4 * 8];
  half8 a1 = *(const half8*)&qt[w * 16 + l15][32 + l4 * 8];
#pragma unroll
  for (int mf = 0; mf < 16; ++mf) {
    half8 b0 = *(const half8*)(om + (size_t)(mf * 16 + l15) * 64 + l4 * 8);
    half8 b1 = *(const half8*)(om + (size_t)(mf * 16 + l15) * 64 + 32 + l4 * 8);
    f32x4 f = {};
    f = __builtin_amdgcn_mfma_f32_16x16x32_f16(a0, b0, f, 0, 0, 0);
    f = __builtin_amdgcn_mfma_f32_16x16x32_f16(a1, b1, f, 0, 0, 0);
#pragma unroll
    for (int r = 0; r < 4; ++r) {
      int n = w * 16 + l4 * 4 + r;
      float p = __expf(f[r] - nrm[n]) * 0.0625f;
      pq[n][mf * 16 + l15] = f2bf(p);
    }
  }
  __syncthreads();
  // out[n][j] = sum_m pq[n][m] * kvt[j][m]; j 0..63 = d, j=64 = z
  f32x4 oacc[5] = {};
#pragma unroll
  for (int ks = 0; ks < 8; ++ks) {
    short8 pa = *(const short8*)&pq[w * 16 + l15][ks * 32 + l4 * 8];
#pragma unroll
    for (int cf = 0; cf < 5; ++cf) {
      short8 bv = *(const short8*)(kvt + ((size_t)bh * 80 + cf * 16 + l15) * 256 + ks * 32 + l4 * 8);
      oacc[cf] = __builtin_amdgcn_mfma_f32_16x16x32_bf16(pa, bv, oacc[cf], 0, 0, 0);
    }
  }
#pragma unroll
  for (int r = 0; r < 4; ++r) {
    float z = __shfl(oacc[4][r], lane & 48);  // j==64 lives in lanes with (lane&15)==0
    float inv = 1.0f / (z + 1e-6f);
    int n = n0 + w * 16 + l4 * 4 + r;
#pragma unroll
    for (int cf = 0; cf < 4; ++cf)
      outp[(size_t)(b * 4096 + n) * 1024 + h * 64 + cf * 16 + l15] = oacc[cf][r] * inv;
  }
}

extern "C" void kernel_launch(void* const* d_in, const int* in_sizes, int n_in,
                              void* d_out, int out_size, void* d_ws, size_t ws_size,
                              hipStream_t stream) {
  const float* x = (const float*)d_in[0];
  const float* Wq = (const float*)d_in[1];
  const float* Wk = (const float*)d_in[2];
  const float* Wv = (const float*)d_in[3];
  const float* omg = (const float*)d_in[4];
  float* outp = (float*)d_out;
  char* ws = (char*)d_ws;

  // ws layout (bytes), total 147,423,232 (~141 MB)
  _Float16* wt = (_Float16*)(ws);                 // 6,291,456
  _Float16* om = (_Float16*)(ws + 6291456);       //    32,768
  ushort_t* qkv = (ushort_t*)(ws + 6324224);      // 100,663,296
  ushort_t* vT = (ushort_t*)(ws + 106987520);     // 33,554,432
  float* kv = (float*)(ws + 140541952);           // 4,194,304
  float* pksum = (float*)(ws + 144736256);        //    65,536
  ushort_t* kvt = (ushort_t*)(ws + 144801792);    // 2,621,440

  k_wtrans<<<dim3(32, 32, 3), dim3(32, 8), 0, stream>>>(Wq, Wk, Wv, wt);
  k_omconv<<<dim3(64), dim3(256), 0, stream>>>(omg, om);
  k_gemm<<<dim3(128, 24), dim3(256), 0, stream>>>(x, wt, qkv);
  k_vtrans<<<dim3(64, 64), dim3(256), 0, stream>>>(qkv, vT);
  hipMemsetAsync(kv, 0, 4194304 + 65536, stream);  // kv + pksum (contiguous)
  k_kv<<<dim3(64, 8), dim3(256), 0, stream>>>(qkv, vT, om, kv, pksum);
  k_kvt<<<dim3(64), dim3(256), 0, stream>>>(kv, pksum, kvt);
  k_out<<<dim3(64, 64), dim3(256), 0, stream>>>(qkv, kvt, om, outp);
}

// Round 2
// 385.571 us; speedup vs baseline: 1.0375x; 1.0375x over previous
//
#include <hip/hip_runtime.h>

// Performer (FAVOR+) attention, MI355X.
// B=4 N=4096 H=16 D=64 DIM=1024 M=256.
// Pipeline:
//  k_wtrans:  W[k][n] f32 -> wt[g][n][k] fp16   (B^T layout for MFMA)
//  k_omconv:  omega f32 -> fp16 (already [m][d] = B^T layout)
//  k_xconv:   x f32 -> xh fp16 (so GEMM staging is pure global_load_lds)
//  k_gemm:    qkv[row][col] = xh @ [Wq|Wk|Wv]; Q,K stored fp16, V stored bf16
//             m97 structure: 128x128 tile, BK=32, dbuf LDS, global_load_lds w16,
//             linear LDS dest + pre-swizzled source + swizzled ds_read (rule #21)
//  k_vtrans:  vT[bh][d][n] (bf16) for kv-stage B operand
//  k_kv:      pk = exp(k.om^T - |k|^2/2)/16 ; kv[bh][m][d] += pk^T v ; pksum
//  k_kvt:     kvt[bh][j][m] bf16: rows 0..63 = kv^T, row 64 = pksum, 65..79 = 0
//  k_out:     pq = exp(q.om^T - |q|^2/2)/16 ; out = (pq@kv) / (pq@pksum + 1e-6)

typedef _Float16 half8 __attribute__((ext_vector_type(8)));
typedef short short8 __attribute__((ext_vector_type(8)));
typedef float f32x4 __attribute__((ext_vector_type(4)));
typedef unsigned short ushort_t;
typedef unsigned int uint_t;

#define QKV_LD 3072

__device__ __forceinline__ ushort_t f2bf(float f) {
  uint_t u = __builtin_bit_cast(uint_t, f);
  u += 0x7fffu + ((u >> 16) & 1u);
  return (ushort_t)(u >> 16);
}

__device__ __forceinline__ void gload16(const void* g, void* l) {
  __builtin_amdgcn_global_load_lds(
      (const __attribute__((address_space(1))) void*)g,
      (__attribute__((address_space(3))) void*)l, 16, 0, 0);
}

// ---------------- W transpose+convert: wt[g][n][k] = (f16)W_g[k][n] ----------------
__global__ void k_wtrans(const float* __restrict__ Wq, const float* __restrict__ Wk,
                         const float* __restrict__ Wv, _Float16* __restrict__ wt) {
  __shared__ float t[32][33];
  const int g = blockIdx.z;
  const float* W = (g == 0) ? Wq : ((g == 1) ? Wk : Wv);
  const int n0 = blockIdx.x * 32, k0 = blockIdx.y * 32;
  const int tx = threadIdx.x, ty = threadIdx.y;
#pragma unroll
  for (int j = 0; j < 4; ++j)
    t[ty + j * 8][tx] = W[(size_t)(k0 + ty + j * 8) * 1024 + n0 + tx];
  __syncthreads();
  _Float16* o = wt + (size_t)g * 1024 * 1024;
#pragma unroll
  for (int j = 0; j < 4; ++j)
    o[(size_t)(n0 + ty + j * 8) * 1024 + k0 + tx] = (_Float16)t[tx][ty + j * 8];
}

__global__ void k_omconv(const float* __restrict__ omega, _Float16* __restrict__ om) {
  int i = blockIdx.x * 256 + threadIdx.x;
  if (i < 16384) om[i] = (_Float16)omega[i];
}

// ---------------- x convert: xh[n][k] = (f16)x[n][k] ----------------
__global__ __launch_bounds__(256) void k_xconv(const float* __restrict__ x,
                                               _Float16* __restrict__ xh) {
  size_t base = ((size_t)blockIdx.x * 256 + threadIdx.x) * 8;
  float4 f0 = *(const float4*)(x + base);
  float4 f1 = *(const float4*)(x + base + 4);
  half8 h;
  h[0] = (_Float16)f0.x; h[1] = (_Float16)f0.y; h[2] = (_Float16)f0.z; h[3] = (_Float16)f0.w;
  h[4] = (_Float16)f1.x; h[5] = (_Float16)f1.y; h[6] = (_Float16)f1.z; h[7] = (_Float16)f1.w;
  *(half8*)(xh + base) = h;
}

// ---------------- QKV GEMM: 128x128 tile, BK=32, global_load_lds, dbuf ----------------
__global__ __launch_bounds__(256) void k_gemm(const _Float16* __restrict__ xh,
                                              const _Float16* __restrict__ wt,
                                              ushort_t* __restrict__ qkv) {
  __shared__ _Float16 As[2][128 * 32];  // linear, 8KB per buf
  __shared__ _Float16 Bs[2][128 * 32];
  const int col0 = blockIdx.x * 128;  // x fast: 24 consecutive blocks share A panel
  const int row0 = blockIdx.y * 128;
  const int g = col0 >> 10;  // 0=Q 1=K 2=V
  const int col0g = col0 & 1023;
  const _Float16* wtg = wt + (size_t)g * (1024 * 1024);
  const int tid = threadIdx.x;
  const int lane = tid & 63;
  const int w = tid >> 6;
  const int wr = w >> 1, wc = w & 1;
  const int l15 = lane & 15, l4 = lane >> 4;

  // staging source coords (pre-swizzled so linear LDS dest + swizzled read agree)
  // idx16 = (i*4+w)*64+lane ; row=idx16>>2 ; c16=idx16&3 ; src col16 = c16 ^ ((row>>1)&3)
  int srow[2], scol[2];
#pragma unroll
  for (int i = 0; i < 2; ++i) {
    int idx16 = (i * 4 + w) * 64 + lane;
    int r = idx16 >> 2, c = idx16 & 3;
    srow[i] = r;
    scol[i] = (c ^ ((r >> 1) & 3)) * 8;
  }

  f32x4 acc[4][4] = {};

  auto stage = [&](int buf, int kt) {
#pragma unroll
    for (int i = 0; i < 2; ++i) {
      gload16(xh + (size_t)(row0 + srow[i]) * 1024 + kt * 32 + scol[i],
              &As[buf][(i * 4 + w) * 512]);
      gload16(wtg + (size_t)(col0g + srow[i]) * 1024 + kt * 32 + scol[i],
              &Bs[buf][(i * 4 + w) * 512]);
    }
  };
  auto compute = [&](int buf) {
    half8 a[4], bb[4];
#pragma unroll
    for (int m = 0; m < 4; ++m) {
      int row = wr * 64 + m * 16 + l15;
      int c16 = l4 ^ ((row >> 1) & 3);
      a[m] = *(const half8*)&As[buf][row * 32 + c16 * 8];
    }
#pragma unroll
    for (int n = 0; n < 4; ++n) {
      int row = wc * 64 + n * 16 + l15;
      int c16 = l4 ^ ((row >> 1) & 3);
      bb[n] = *(const half8*)&Bs[buf][row * 32 + c16 * 8];
    }
#pragma unroll
    for (int m = 0; m < 4; ++m)
#pragma unroll
      for (int n = 0; n < 4; ++n)
        acc[m][n] = __builtin_amdgcn_mfma_f32_16x16x32_f16(a[m], bb[n], acc[m][n], 0, 0, 0);
  };

  stage(0, 0);
  __syncthreads();  // compiler emits vmcnt(0) drain before barrier
  for (int kt = 0; kt < 31; ++kt) {
    stage((kt + 1) & 1, kt + 1);
    compute(kt & 1);
    __syncthreads();
  }
  compute(1);

  // epilogue: C row = (lane>>4)*4+reg, col = lane&15
#pragma unroll
  for (int m = 0; m < 4; ++m) {
    int gr0 = row0 + wr * 64 + m * 16 + l4 * 4;
#pragma unroll
    for (int n = 0; n < 4; ++n) {
      int gc = col0 + wc * 64 + n * 16 + l15;
#pragma unroll
      for (int r = 0; r < 4; ++r) {
        float v = acc[m][n][r];
        ushort_t bits = (g == 2) ? f2bf(v) : __builtin_bit_cast(ushort_t, (_Float16)v);
        qkv[(size_t)(gr0 + r) * QKV_LD + gc] = bits;
      }
    }
  }
}

// ---------------- V transpose: vT[bh][d][n] = qkv_V[b n][h*64+d] ----------------
__global__ __launch_bounds__(256) void k_vtrans(const ushort_t* __restrict__ qkv,
                                                ushort_t* __restrict__ vT) {
  __shared__ ushort_t tile[64][72];
  const int bh = blockIdx.x;
  const int nc = blockIdx.y;
  const int b = bh >> 4, h = bh & 15;
  const int n0 = nc * 64;
  const int tid = threadIdx.x;
#pragma unroll
  for (int i = 0; i < 2; ++i) {
    int c = i * 256 + tid;
    int r = c >> 3, s = c & 7;
    const ushort_t* src = qkv + (size_t)(b * 4096 + n0 + r) * QKV_LD + 2048 + h * 64 + s * 8;
    *(short8*)&tile[r][s * 8] = *(const short8*)src;
  }
  __syncthreads();
#pragma unroll
  for (int i = 0; i < 2; ++i) {
    int c = i * 256 + tid;
    int d = c >> 3, s = c & 7;
    short8 v;
#pragma unroll
    for (int j = 0; j < 8; ++j) v[j] = (short)tile[s * 8 + j][d];
    *(short8*)(vT + (size_t)(bh * 64 + d) * 4096 + n0 + s * 8) = v;
  }
}

// ---------------- fused phi(k) + kv accumulation ----------------
__global__ __launch_bounds__(256) void k_kv(const ushort_t* __restrict__ qkv,
                                            const ushort_t* __restrict__ vT,
                                            const _Float16* __restrict__ om,
                                            float* __restrict__ kv,
                                            float* __restrict__ pksum) {
  __shared__ _Float16 kt[64][72];
  __shared__ ushort_t vt[64][72];
  __shared__ ushort_t pk[256][72];  // [m][n], rows 144B
  __shared__ float nrm[64];
  const int bh = blockIdx.x, split = blockIdx.y;
  const int b = bh >> 4, h = bh & 15;
  const int tid = threadIdx.x, lane = tid & 63, w = tid >> 6;
  const int l15 = lane & 15, l4 = lane >> 4;

  half8 bom[4][2];
#pragma unroll
  for (int mf = 0; mf < 4; ++mf)
#pragma unroll
    for (int ks = 0; ks < 2; ++ks)
      bom[mf][ks] = *(const half8*)(om + (size_t)(w * 64 + mf * 16 + l15) * 64 + ks * 32 + l4 * 8);

  f32x4 kvacc[4][4] = {};
  float psum[4] = {0.f, 0.f, 0.f, 0.f};

  for (int ch = 0; ch < 8; ++ch) {
    const int nbase = split * 512 + ch * 64;
#pragma unroll
    for (int i = 0; i < 2; ++i) {
      int c = i * 256 + tid;
      int r = c >> 3, s = c & 7;
      *(short8*)&kt[r][s * 8] =
          *(const short8*)(qkv + (size_t)(b * 4096 + nbase + r) * QKV_LD + 1024 + h * 64 + s * 8);
      *(short8*)&vt[r][s * 8] =
          *(const short8*)(vT + (size_t)(bh * 64 + r) * 4096 + nbase + s * 8);
    }
    __syncthreads();
    {  // row norms: 4 threads per row
      int row = tid >> 2, part = tid & 3;
      float sm = 0.f;
#pragma unroll
      for (int i = 0; i < 16; ++i) {
        float kf = (float)kt[row][part * 16 + i];
        sm += kf * kf;
      }
      sm += __shfl_xor(sm, 1);
      sm += __shfl_xor(sm, 2);
      if ((tid & 3) == 0) nrm[row] = 0.5f * sm;
    }
    __syncthreads();
#pragma unroll
    for (int nf = 0; nf < 4; ++nf) {
      half8 a0 = *(const half8*)&kt[nf * 16 + l15][l4 * 8];
      half8 a1 = *(const half8*)&kt[nf * 16 + l15][32 + l4 * 8];
#pragma unroll
      for (int mf = 0; mf < 4; ++mf) {
        f32x4 f = {};
        f = __builtin_amdgcn_mfma_f32_16x16x32_f16(a0, bom[mf][0], f, 0, 0, 0);
        f = __builtin_amdgcn_mfma_f32_16x16x32_f16(a1, bom[mf][1], f, 0, 0, 0);
#pragma unroll
        for (int r = 0; r < 4; ++r) {
          int n = nf * 16 + l4 * 4 + r;
          float p = __expf(f[r] - nrm[n]) * 0.0625f;
          pk[w * 64 + mf * 16 + l15][n] = f2bf(p);
          psum[mf] += p;
        }
      }
    }
    __syncthreads();
#pragma unroll
    for (int ks = 0; ks < 2; ++ks) {
      short8 pa[4];
#pragma unroll
      for (int mf = 0; mf < 4; ++mf)
        pa[mf] = *(const short8*)&pk[w * 64 + mf * 16 + l15][ks * 32 + l4 * 8];
#pragma unroll
      for (int df = 0; df < 4; ++df) {
        short8 bv = *(const short8*)&vt[df * 16 + l15][ks * 32 + l4 * 8];
#pragma unroll
        for (int mf = 0; mf < 4; ++mf)
          kvacc[mf][df] = __builtin_amdgcn_mfma_f32_16x16x32_bf16(pa[mf], bv, kvacc[mf][df], 0, 0, 0);
      }
    }
    __syncthreads();
  }
#pragma unroll
  for (int mf = 0; mf < 4; ++mf)
#pragma unroll
    for (int df = 0; df < 4; ++df)
#pragma unroll
      for (int r = 0; r < 4; ++r) {
        int m = w * 64 + mf * 16 + l4 * 4 + r;
        int d = df * 16 + l15;
        atomicAdd(&kv[((size_t)bh * 256 + m) * 64 + d], kvacc[mf][df][r]);
      }
#pragma unroll
  for (int mf = 0; mf < 4; ++mf) {
    float v = psum[mf];
    v += __shfl_xor(v, 16);
    v += __shfl_xor(v, 32);
    if (lane < 16) atomicAdd(&pksum[bh * 256 + w * 64 + mf * 16 + lane], v);
  }
}

// ---------------- kv -> kvt (B^T bf16, + pksum row 64, zero pad rows) ----------------
__global__ __launch_bounds__(256) void k_kvt(const float* __restrict__ kv,
                                             const float* __restrict__ pksum,
                                             ushort_t* __restrict__ kvt) {
  const int bh = blockIdx.x, tid = threadIdx.x;
  const int d = tid >> 2, mb = (tid & 3) * 64;
  for (int j = 0; j < 64; ++j) {
    int m = mb + j;
    kvt[((size_t)bh * 80 + d) * 256 + m] = f2bf(kv[((size_t)bh * 256 + m) * 64 + d]);
  }
  kvt[((size_t)bh * 80 + 64) * 256 + tid] = f2bf(pksum[bh * 256 + tid]);
  for (int r = 65; r < 80; ++r) kvt[((size_t)bh * 80 + r) * 256 + tid] = 0;
}

// ---------------- fused phi(q) + out ----------------
__global__ __launch_bounds__(256) void k_out(const ushort_t* __restrict__ qkv,
                                             const ushort_t* __restrict__ kvt,
                                             const _Float16* __restrict__ om,
                                             float* __restrict__ outp) {
  __shared__ _Float16 qt[64][72];
  __shared__ ushort_t pq[64][264];  // [n][m], rows 528B
  __shared__ float nrm[64];
  const int bh = blockIdx.x, nc = blockIdx.y;
  const int b = bh >> 4, h = bh & 15;
  const int n0 = nc * 64;
  const int tid = threadIdx.x, lane = tid & 63, w = tid >> 6;
  const int l15 = lane & 15, l4 = lane >> 4;
#pragma unroll
  for (int i = 0; i < 2; ++i) {
    int c = i * 256 + tid;
    int r = c >> 3, s = c & 7;
    *(short8*)&qt[r][s * 8] =
        *(const short8*)(qkv + (size_t)(b * 4096 + n0 + r) * QKV_LD + h * 64 + s * 8);
  }
  __syncthreads();
  {
    int row = tid >> 2, part = tid & 3;
    float sm = 0.f;
#pragma unroll
    for (int i = 0; i < 16; ++i) {
      float qf = (float)qt[row][part * 16 + i];
      sm += qf * qf;
    }
    sm += __shfl_xor(sm, 1);
    sm += __shfl_xor(sm, 2);
    if ((tid & 3) == 0) nrm[row] = 0.5f * sm;
  }
  __syncthreads();
  half8 a0 = *(const half8*)&qt[w * 16 + l15][l4 * 8];
  half8 a1 = *(const half8*)&qt[w * 16 + l15][32 + l4 * 8];
#pragma unroll
  for (int mf = 0; mf < 16; ++mf) {
    half8 b0 = *(const half8*)(om + (size_t)(mf * 16 + l15) * 64 + l4 * 8);
    half8 b1 = *(const half8*)(om + (size_t)(mf * 16 + l15) * 64 + 32 + l4 * 8);
    f32x4 f = {};
    f = __builtin_amdgcn_mfma_f32_16x16x32_f16(a0, b0, f, 0, 0, 0);
    f = __builtin_amdgcn_mfma_f32_16x16x32_f16(a1, b1, f, 0, 0, 0);
#pragma unroll
    for (int r = 0; r < 4; ++r) {
      int n = w * 16 + l4 * 4 + r;
      float p = __expf(f[r] - nrm[n]) * 0.0625f;
      pq[n][mf * 16 + l15] = f2bf(p);
    }
  }
  __syncthreads();
  f32x4 oacc[5] = {};
#pragma unroll
  for (int ks = 0; ks < 8; ++ks) {
    short8 pa = *(const short8*)&pq[w * 16 + l15][ks * 32 + l4 * 8];
#pragma unroll
    for (int cf = 0; cf < 5; ++cf) {
      short8 bv = *(const short8*)(kvt + ((size_t)bh * 80 + cf * 16 + l15) * 256 + ks * 32 + l4 * 8);
      oacc[cf] = __builtin_amdgcn_mfma_f32_16x16x32_bf16(pa, bv, oacc[cf], 0, 0, 0);
    }
  }
#pragma unroll
  for (int r = 0; r < 4; ++r) {
    float z = __shfl(oacc[4][r], lane & 48);
    float inv = 1.0f / (z + 1e-6f);
    int n = n0 + w * 16 + l4 * 4 + r;
#pragma unroll
    for (int cf = 0; cf < 4; ++cf)
      outp[(size_t)(b * 4096 + n) * 1024 + h * 64 + cf * 16 + l15] = oacc[cf][r] * inv;
  }
}

extern "C" void kernel_launch(void* const* d_in, const int* in_sizes, int n_in,
                              void* d_out, int out_size, void* d_ws, size_t ws_size,
                              hipStream_t stream) {
  const float* x = (const float*)d_in[0];
  const float* Wq = (const float*)d_in[1];
  const float* Wk = (const float*)d_in[2];
  const float* Wv = (const float*)d_in[3];
  const float* omg = (const float*)d_in[4];
  float* outp = (float*)d_out;
  char* ws = (char*)d_ws;

  // ws layout (bytes), total 147,423,232 (~141 MB)
  // xh (33.5 MB) aliases vT: xh is dead after k_gemm; vT written after.
  _Float16* wt = (_Float16*)(ws);                 // 6,291,456
  _Float16* om = (_Float16*)(ws + 6291456);       //    32,768
  ushort_t* qkv = (ushort_t*)(ws + 6324224);      // 100,663,296
  _Float16* xh = (_Float16*)(ws + 106987520);     // 33,554,432 (aliases vT)
  ushort_t* vT = (ushort_t*)(ws + 106987520);     // 33,554,432
  float* kv = (float*)(ws + 140541952);           // 4,194,304
  float* pksum = (float*)(ws + 144736256);        //    65,536
  ushort_t* kvt = (ushort_t*)(ws + 144801792);    // 2,621,440

  k_wtrans<<<dim3(32, 32, 3), dim3(32, 8), 0, stream>>>(Wq, Wk, Wv, wt);
  k_omconv<<<dim3(64), dim3(256), 0, stream>>>(omg, om);
  k_xconv<<<dim3(8192), dim3(256), 0, stream>>>(x, xh);
  k_gemm<<<dim3(24, 128), dim3(256), 0, stream>>>(xh, wt, qkv);
  k_vtrans<<<dim3(64, 64), dim3(256), 0, stream>>>(qkv, vT);
  hipMemsetAsync(kv, 0, 4194304 + 65536, stream);  // kv + pksum (contiguous)
  k_kv<<<dim3(64, 8), dim3(256), 0, stream>>>(qkv, vT, om, kv, pksum);
  k_kvt<<<dim3(64), dim3(256), 0, stream>>>(kv, pksum, kvt);
  k_out<<<dim3(64, 64), dim3(256), 0, stream>>>(qkv, kvt, om, outp);
}

// Round 3
// 355.834 us; speedup vs baseline: 1.1242x; 1.0836x over previous
//
#include <hip/hip_runtime.h>

// Performer (FAVOR+) attention, MI355X.
// B=4 N=4096 H=16 D=64 DIM=1024 M=256.
// Pipeline:
//  k_wtrans:  W[k][n] f32 -> wt[g][n][k] fp16   (B^T layout for MFMA)
//  k_omconv:  omega f32 -> fp16
//  k_xconv:   x f32 -> xh fp16
//  k_gemm:    qkv = xh @ [Wq|Wk|Wv]; 256x256 tile, BK=32, 8 waves,
//             3-buffer LDS pipeline, counted vmcnt(6) (T3+T4), raw s_barrier,
//             setprio (T5), block-linear [16][32] subtile + XOR swizzle (T2),
//             global_load_lds w16 with pre-swizzled source (rule #21).
//  k_vtrans:  vT[bh][d][n] (bf16)
//  k_kv:      pk = exp(k.om^T - |k|^2/2)/16 ; kv += pk^T v ; pksum  (b64-packed pk stores)
//  k_kvt:     kvt[bh][j][m] bf16: rows 0..63 = kv^T, row 64 = pksum, 65..79 = 0
//  k_out:     pq = exp(q.om^T - |q|^2/2)/16 ; out = (pq@kv) / (pq@pksum + 1e-6)

typedef _Float16 half8 __attribute__((ext_vector_type(8)));
typedef short short8 __attribute__((ext_vector_type(8)));
typedef float f32x4 __attribute__((ext_vector_type(4)));
typedef unsigned short ushort4v __attribute__((ext_vector_type(4)));
typedef unsigned short ushort_t;
typedef unsigned int uint_t;

#define QKV_LD 3072

__device__ __forceinline__ ushort_t f2bf(float f) {
  uint_t u = __builtin_bit_cast(uint_t, f);
  u += 0x7fffu + ((u >> 16) & 1u);
  return (ushort_t)(u >> 16);
}

__device__ __forceinline__ void gload16(const void* g, void* l) {
  __builtin_amdgcn_global_load_lds(
      (const __attribute__((address_space(1))) void*)g,
      (__attribute__((address_space(3))) void*)l, 16, 0, 0);
}

// ---------------- W transpose+convert: wt[g][n][k] = (f16)W_g[k][n] ----------------
__global__ void k_wtrans(const float* __restrict__ Wq, const float* __restrict__ Wk,
                         const float* __restrict__ Wv, _Float16* __restrict__ wt) {
  __shared__ float t[32][33];
  const int g = blockIdx.z;
  const float* W = (g == 0) ? Wq : ((g == 1) ? Wk : Wv);
  const int n0 = blockIdx.x * 32, k0 = blockIdx.y * 32;
  const int tx = threadIdx.x, ty = threadIdx.y;
#pragma unroll
  for (int j = 0; j < 4; ++j)
    t[ty + j * 8][tx] = W[(size_t)(k0 + ty + j * 8) * 1024 + n0 + tx];
  __syncthreads();
  _Float16* o = wt + (size_t)g * 1024 * 1024;
#pragma unroll
  for (int j = 0; j < 4; ++j)
    o[(size_t)(n0 + ty + j * 8) * 1024 + k0 + tx] = (_Float16)t[tx][ty + j * 8];
}

__global__ void k_omconv(const float* __restrict__ omega, _Float16* __restrict__ om) {
  int i = blockIdx.x * 256 + threadIdx.x;
  if (i < 16384) om[i] = (_Float16)omega[i];
}

// ---------------- x convert: xh[n][k] = (f16)x[n][k] ----------------
__global__ __launch_bounds__(256) void k_xconv(const float* __restrict__ x,
                                               _Float16* __restrict__ xh) {
  size_t base = ((size_t)blockIdx.x * 256 + threadIdx.x) * 8;
  float4 f0 = *(const float4*)(x + base);
  float4 f1 = *(const float4*)(x + base + 4);
  half8 h;
  h[0] = (_Float16)f0.x; h[1] = (_Float16)f0.y; h[2] = (_Float16)f0.z; h[3] = (_Float16)f0.w;
  h[4] = (_Float16)f1.x; h[5] = (_Float16)f1.y; h[6] = (_Float16)f1.z; h[7] = (_Float16)f1.w;
  *(half8*)(xh + base) = h;
}

// ---------------- QKV GEMM: 256x256 tile, BK=32, 3-buf pipeline, counted vmcnt ----------------
// LDS element layout per buffer (A and B identical, 256 rows x 32 k-cols):
//   subtile rb = row>>4 (16 rows x 32 cols, 1024B contiguous)
//   elem off = rb*512 + (row&15)*32 + (col ^ (((row&8))?16:0))   [T2 swizzle]
// Staged linearly by global_load_lds; source address pre-swizzled (involution).
__global__ __launch_bounds__(512, 2) void k_gemm(const _Float16* __restrict__ xh,
                                                 const _Float16* __restrict__ wt,
                                                 ushort_t* __restrict__ qkv) {
  __shared__ _Float16 As[3][8192];
  __shared__ _Float16 Bs[3][8192];
  // XCD-aware swizzle: grid 768 = 8 XCDs x 96 contiguous tiles
  const int vb = (blockIdx.x & 7) * 96 + (blockIdx.x >> 3);
  const int ct = vb % 12, rt = vb / 12;
  const int col0 = ct * 256, row0 = rt * 256;
  const int g = col0 >> 10;  // 0=Q 1=K 2=V (256 | 1024)
  const int col0g = col0 & 1023;
  const _Float16* wtg = wt + (size_t)g * (1024 * 1024);
  const int tid = threadIdx.x;
  const int lane = tid & 63;
  const int w = tid >> 6;
  const int wm = w >> 2, wn = w & 3;  // wave tile: rows [wm*128,+128), cols [wn*64,+64)
  const int l15 = lane & 15, l4 = lane >> 4;

  // staging coords: thread covers LDS bytes (i*512+tid)*16 of the 16KB tile
  int srow[2], scol[2], dst[2];
#pragma unroll
  for (int i = 0; i < 2; ++i) {
    int u = i * 512 + tid;
    int rb = u >> 6, rr = (u >> 2) & 15, ccb = u & 3;
    srow[i] = rb * 16 + rr;
    scol[i] = (ccb * 8) ^ ((rr & 8) ? 16 : 0);  // pre-swizzled source col
    dst[i] = u * 8;                             // f16 elements
  }
  // swizzled k-col for fragment reads
  const int kx = (l4 * 8) ^ ((l15 & 8) ? 16 : 0);

  auto stageA = [&](int b, int kt) {
#pragma unroll
    for (int i = 0; i < 2; ++i)
      gload16(xh + (size_t)(row0 + srow[i]) * 1024 + kt * 32 + scol[i], &As[b][dst[i]]);
  };
  auto stageB = [&](int b, int kt) {
#pragma unroll
    for (int i = 0; i < 2; ++i)
      gload16(wtg + (size_t)(col0g + srow[i]) * 1024 + kt * 32 + scol[i], &Bs[b][dst[i]]);
  };

  f32x4 acc[8][4] = {};

  stageA(0, 0); stageB(0, 0);
  stageA(1, 1); stageB(1, 1);

  int b = 0;
  for (int kt = 0; kt < 32; ++kt) {
    int b2 = b + 2; if (b2 >= 3) b2 -= 3;
    if (kt < 30) stageA(b2, kt + 2);
    // counted wait: tile kt fully landed (6 newer loads stay in flight)
    if (kt < 30)       asm volatile("s_waitcnt vmcnt(6)" ::: "memory");
    else if (kt == 30) asm volatile("s_waitcnt vmcnt(4)" ::: "memory");
    else               asm volatile("s_waitcnt vmcnt(0)" ::: "memory");
    asm volatile("s_barrier" ::: "memory");

    const _Float16* Ab = &As[b][0];
    const _Float16* Bb = &Bs[b][0];
    half8 av[4], bv[4];
#pragma unroll
    for (int mi = 0; mi < 4; ++mi)
      av[mi] = *(const half8*)&Ab[(wm * 8 + mi) * 512 + l15 * 32 + kx];
#pragma unroll
    for (int ni = 0; ni < 4; ++ni)
      bv[ni] = *(const half8*)&Bb[(wn * 4 + ni) * 512 + l15 * 32 + kx];
    if (kt < 30) stageB(b2, kt + 2);
    __builtin_amdgcn_s_setprio(1);
#pragma unroll
    for (int mi = 0; mi < 4; ++mi)
#pragma unroll
      for (int ni = 0; ni < 4; ++ni)
        acc[mi][ni] = __builtin_amdgcn_mfma_f32_16x16x32_f16(av[mi], bv[ni], acc[mi][ni], 0, 0, 0);
    __builtin_amdgcn_s_setprio(0);
    asm volatile("s_barrier" ::: "memory");

    half8 av2[4];
#pragma unroll
    for (int mi = 0; mi < 4; ++mi)
      av2[mi] = *(const half8*)&Ab[(wm * 8 + 4 + mi) * 512 + l15 * 32 + kx];
    __builtin_amdgcn_s_setprio(1);
#pragma unroll
    for (int mi = 0; mi < 4; ++mi)
#pragma unroll
      for (int ni = 0; ni < 4; ++ni)
        acc[4 + mi][ni] = __builtin_amdgcn_mfma_f32_16x16x32_f16(av2[mi], bv[ni], acc[4 + mi][ni], 0, 0, 0);
    __builtin_amdgcn_s_setprio(0);

    b = b + 1; if (b == 3) b = 0;
  }

  // epilogue: C row = (lane>>4)*4+reg, col = lane&15
#pragma unroll
  for (int mi = 0; mi < 8; ++mi) {
    int gr0 = row0 + wm * 128 + mi * 16 + l4 * 4;
#pragma unroll
    for (int ni = 0; ni < 4; ++ni) {
      int gc = col0 + wn * 64 + ni * 16 + l15;
#pragma unroll
      for (int r = 0; r < 4; ++r) {
        float v = acc[mi][ni][r];
        ushort_t bits = (g == 2) ? f2bf(v) : __builtin_bit_cast(ushort_t, (_Float16)v);
        qkv[(size_t)(gr0 + r) * QKV_LD + gc] = bits;
      }
    }
  }
}

// ---------------- V transpose: vT[bh][d][n] = qkv_V[b n][h*64+d] ----------------
__global__ __launch_bounds__(256) void k_vtrans(const ushort_t* __restrict__ qkv,
                                                ushort_t* __restrict__ vT) {
  __shared__ ushort_t tile[64][72];
  const int bh = blockIdx.x;
  const int nc = blockIdx.y;
  const int b = bh >> 4, h = bh & 15;
  const int n0 = nc * 64;
  const int tid = threadIdx.x;
#pragma unroll
  for (int i = 0; i < 2; ++i) {
    int c = i * 256 + tid;
    int r = c >> 3, s = c & 7;
    const ushort_t* src = qkv + (size_t)(b * 4096 + n0 + r) * QKV_LD + 2048 + h * 64 + s * 8;
    *(short8*)&tile[r][s * 8] = *(const short8*)src;
  }
  __syncthreads();
#pragma unroll
  for (int i = 0; i < 2; ++i) {
    int c = i * 256 + tid;
    int d = c >> 3, s = c & 7;
    short8 v;
#pragma unroll
    for (int j = 0; j < 8; ++j) v[j] = (short)tile[s * 8 + j][d];
    *(short8*)(vT + (size_t)(bh * 64 + d) * 4096 + n0 + s * 8) = v;
  }
}

// ---------------- fused phi(k) + kv accumulation ----------------
__global__ __launch_bounds__(256) void k_kv(const ushort_t* __restrict__ qkv,
                                            const ushort_t* __restrict__ vT,
                                            const _Float16* __restrict__ om,
                                            float* __restrict__ kv,
                                            float* __restrict__ pksum) {
  __shared__ _Float16 kt[64][72];
  __shared__ ushort_t vt[64][72];
  __shared__ ushort_t pk[256][72];  // [m][n], rows 144B
  __shared__ float nrm[64];
  const int bh = blockIdx.x, split = blockIdx.y;
  const int b = bh >> 4, h = bh & 15;
  const int tid = threadIdx.x, lane = tid & 63, w = tid >> 6;
  const int l15 = lane & 15, l4 = lane >> 4;

  half8 bom[4][2];
#pragma unroll
  for (int mf = 0; mf < 4; ++mf)
#pragma unroll
    for (int ks = 0; ks < 2; ++ks)
      bom[mf][ks] = *(const half8*)(om + (size_t)(w * 64 + mf * 16 + l15) * 64 + ks * 32 + l4 * 8);

  f32x4 kvacc[4][4] = {};
  float psum[4] = {0.f, 0.f, 0.f, 0.f};

  for (int ch = 0; ch < 8; ++ch) {
    const int nbase = split * 512 + ch * 64;
#pragma unroll
    for (int i = 0; i < 2; ++i) {
      int c = i * 256 + tid;
      int r = c >> 3, s = c & 7;
      *(short8*)&kt[r][s * 8] =
          *(const short8*)(qkv + (size_t)(b * 4096 + nbase + r) * QKV_LD + 1024 + h * 64 + s * 8);
      *(short8*)&vt[r][s * 8] =
          *(const short8*)(vT + (size_t)(bh * 64 + r) * 4096 + nbase + s * 8);
    }
    __syncthreads();
    {  // row norms: 4 threads per row
      int row = tid >> 2, part = tid & 3;
      float sm = 0.f;
#pragma unroll
      for (int i = 0; i < 16; ++i) {
        float kf = (float)kt[row][part * 16 + i];
        sm += kf * kf;
      }
      sm += __shfl_xor(sm, 1);
      sm += __shfl_xor(sm, 2);
      if ((tid & 3) == 0) nrm[row] = 0.5f * sm;
    }
    __syncthreads();
#pragma unroll
    for (int nf = 0; nf < 4; ++nf) {
      half8 a0 = *(const half8*)&kt[nf * 16 + l15][l4 * 8];
      half8 a1 = *(const half8*)&kt[nf * 16 + l15][32 + l4 * 8];
#pragma unroll
      for (int mf = 0; mf < 4; ++mf) {
        f32x4 f = {};
        f = __builtin_amdgcn_mfma_f32_16x16x32_f16(a0, bom[mf][0], f, 0, 0, 0);
        f = __builtin_amdgcn_mfma_f32_16x16x32_f16(a1, bom[mf][1], f, 0, 0, 0);
        ushort4v pw;
#pragma unroll
        for (int r = 0; r < 4; ++r) {
          int n = nf * 16 + l4 * 4 + r;
          float p = __expf(f[r] - nrm[n]) * 0.0625f;
          psum[mf] += p;
          pw[r] = f2bf(p);
        }
        *(ushort4v*)&pk[w * 64 + mf * 16 + l15][nf * 16 + l4 * 4] = pw;  // one b64 store
      }
    }
    __syncthreads();
#pragma unroll
    for (int ks = 0; ks < 2; ++ks) {
      short8 pa[4];
#pragma unroll
      for (int mf = 0; mf < 4; ++mf)
        pa[mf] = *(const short8*)&pk[w * 64 + mf * 16 + l15][ks * 32 + l4 * 8];
#pragma unroll
      for (int df = 0; df < 4; ++df) {
        short8 bv = *(const short8*)&vt[df * 16 + l15][ks * 32 + l4 * 8];
#pragma unroll
        for (int mf = 0; mf < 4; ++mf)
          kvacc[mf][df] = __builtin_amdgcn_mfma_f32_16x16x32_bf16(pa[mf], bv, kvacc[mf][df], 0, 0, 0);
      }
    }
    __syncthreads();
  }
#pragma unroll
  for (int mf = 0; mf < 4; ++mf)
#pragma unroll
    for (int df = 0; df < 4; ++df)
#pragma unroll
      for (int r = 0; r < 4; ++r) {
        int m = w * 64 + mf * 16 + l4 * 4 + r;
        int d = df * 16 + l15;
        atomicAdd(&kv[((size_t)bh * 256 + m) * 64 + d], kvacc[mf][df][r]);
      }
#pragma unroll
  for (int mf = 0; mf < 4; ++mf) {
    float v = psum[mf];
    v += __shfl_xor(v, 16);
    v += __shfl_xor(v, 32);
    if (lane < 16) atomicAdd(&pksum[bh * 256 + w * 64 + mf * 16 + lane], v);
  }
}

// ---------------- kv -> kvt (B^T bf16, + pksum row 64, zero pad rows) ----------------
__global__ __launch_bounds__(256) void k_kvt(const float* __restrict__ kv,
                                             const float* __restrict__ pksum,
                                             ushort_t* __restrict__ kvt) {
  const int bh = blockIdx.x, tid = threadIdx.x;
  const int d = tid >> 2, mb = (tid & 3) * 64;
  for (int j = 0; j < 64; ++j) {
    int m = mb + j;
    kvt[((size_t)bh * 80 + d) * 256 + m] = f2bf(kv[((size_t)bh * 256 + m) * 64 + d]);
  }
  kvt[((size_t)bh * 80 + 64) * 256 + tid] = f2bf(pksum[bh * 256 + tid]);
  for (int r = 65; r < 80; ++r) kvt[((size_t)bh * 80 + r) * 256 + tid] = 0;
}

// ---------------- fused phi(q) + out ----------------
__global__ __launch_bounds__(256) void k_out(const ushort_t* __restrict__ qkv,
                                             const ushort_t* __restrict__ kvt,
                                             const _Float16* __restrict__ om,
                                             float* __restrict__ outp) {
  __shared__ _Float16 qt[64][72];
  __shared__ ushort_t pq[64][264];  // [n][m], rows 528B
  __shared__ float nrm[64];
  const int bh = blockIdx.x, nc = blockIdx.y;
  const int b = bh >> 4, h = bh & 15;
  const int n0 = nc * 64;
  const int tid = threadIdx.x, lane = tid & 63, w = tid >> 6;
  const int l15 = lane & 15, l4 = lane >> 4;
#pragma unroll
  for (int i = 0; i < 2; ++i) {
    int c = i * 256 + tid;
    int r = c >> 3, s = c & 7;
    *(short8*)&qt[r][s * 8] =
        *(const short8*)(qkv + (size_t)(b * 4096 + n0 + r) * QKV_LD + h * 64 + s * 8);
  }
  __syncthreads();
  {
    int row = tid >> 2, part = tid & 3;
    float sm = 0.f;
#pragma unroll
    for (int i = 0; i < 16; ++i) {
      float qf = (float)qt[row][part * 16 + i];
      sm += qf * qf;
    }
    sm += __shfl_xor(sm, 1);
    sm += __shfl_xor(sm, 2);
    if ((tid & 3) == 0) nrm[row] = 0.5f * sm;
  }
  __syncthreads();
  half8 a0 = *(const half8*)&qt[w * 16 + l15][l4 * 8];
  half8 a1 = *(const half8*)&qt[w * 16 + l15][32 + l4 * 8];
#pragma unroll
  for (int mf = 0; mf < 16; ++mf) {
    half8 b0 = *(const half8*)(om + (size_t)(mf * 16 + l15) * 64 + l4 * 8);
    half8 b1 = *(const half8*)(om + (size_t)(mf * 16 + l15) * 64 + 32 + l4 * 8);
    f32x4 f = {};
    f = __builtin_amdgcn_mfma_f32_16x16x32_f16(a0, b0, f, 0, 0, 0);
    f = __builtin_amdgcn_mfma_f32_16x16x32_f16(a1, b1, f, 0, 0, 0);
#pragma unroll
    for (int r = 0; r < 4; ++r) {
      int n = w * 16 + l4 * 4 + r;
      float p = __expf(f[r] - nrm[n]) * 0.0625f;
      pq[n][mf * 16 + l15] = f2bf(p);
    }
  }
  __syncthreads();
  f32x4 oacc[5] = {};
#pragma unroll
  for (int ks = 0; ks < 8; ++ks) {
    short8 pa = *(const short8*)&pq[w * 16 + l15][ks * 32 + l4 * 8];
#pragma unroll
    for (int cf = 0; cf < 5; ++cf) {
      short8 bv = *(const short8*)(kvt + ((size_t)bh * 80 + cf * 16 + l15) * 256 + ks * 32 + l4 * 8);
      oacc[cf] = __builtin_amdgcn_mfma_f32_16x16x32_bf16(pa, bv, oacc[cf], 0, 0, 0);
    }
  }
#pragma unroll
  for (int r = 0; r < 4; ++r) {
    float z = __shfl(oacc[4][r], lane & 48);
    float inv = 1.0f / (z + 1e-6f);
    int n = n0 + w * 16 + l4 * 4 + r;
#pragma unroll
    for (int cf = 0; cf < 4; ++cf)
      outp[(size_t)(b * 4096 + n) * 1024 + h * 64 + cf * 16 + l15] = oacc[cf][r] * inv;
  }
}

extern "C" void kernel_launch(void* const* d_in, const int* in_sizes, int n_in,
                              void* d_out, int out_size, void* d_ws, size_t ws_size,
                              hipStream_t stream) {
  const float* x = (const float*)d_in[0];
  const float* Wq = (const float*)d_in[1];
  const float* Wk = (const float*)d_in[2];
  const float* Wv = (const float*)d_in[3];
  const float* omg = (const float*)d_in[4];
  float* outp = (float*)d_out;
  char* ws = (char*)d_ws;

  // ws layout (bytes), total 147,423,232 (~141 MB)
  // xh (33.5 MB) aliases vT: xh is dead after k_gemm; vT written after.
  _Float16* wt = (_Float16*)(ws);                 // 6,291,456
  _Float16* om = (_Float16*)(ws + 6291456);       //    32,768
  ushort_t* qkv = (ushort_t*)(ws + 6324224);      // 100,663,296
  _Float16* xh = (_Float16*)(ws + 106987520);     // 33,554,432 (aliases vT)
  ushort_t* vT = (ushort_t*)(ws + 106987520);     // 33,554,432
  float* kv = (float*)(ws + 140541952);           // 4,194,304
  float* pksum = (float*)(ws + 144736256);        //    65,536
  ushort_t* kvt = (ushort_t*)(ws + 144801792);    // 2,621,440

  k_wtrans<<<dim3(32, 32, 3), dim3(32, 8), 0, stream>>>(Wq, Wk, Wv, wt);
  k_omconv<<<dim3(64), dim3(256), 0, stream>>>(omg, om);
  k_xconv<<<dim3(8192), dim3(256), 0, stream>>>(x, xh);
  k_gemm<<<dim3(768), dim3(512), 0, stream>>>(xh, wt, qkv);
  k_vtrans<<<dim3(64, 64), dim3(256), 0, stream>>>(qkv, vT);
  hipMemsetAsync(kv, 0, 4194304 + 65536, stream);  // kv + pksum (contiguous)
  k_kv<<<dim3(64, 8), dim3(256), 0, stream>>>(qkv, vT, om, kv, pksum);
  k_kvt<<<dim3(64), dim3(256), 0, stream>>>(kv, pksum, kvt);
  k_out<<<dim3(64, 64), dim3(256), 0, stream>>>(qkv, kvt, om, outp);
}

// Round 4
// 265.062 us; speedup vs baseline: 1.5092x; 1.3425x over previous
//
#include <hip/hip_runtime.h>

// Performer (FAVOR+) attention, MI355X.
// B=4 N=4096 H=16 D=64 DIM=1024 M=256.
// Pipeline:
//  k_wtrans:  W[k][n] f32 -> wt[g][n][k] fp16   (B^T layout for MFMA)
//  k_omconv:  omega f32 -> fp16
//  k_xconv:   x f32 -> xh fp16
//  k_gemm:    qkv = xh @ [Wq|Wk|Wv]; 256x256 tile, BK=32, 8 waves,
//             3-buffer LDS pipeline, counted vmcnt(6) (T3+T4), raw s_barrier,
//             setprio (T5), block-linear [16][32] subtile + XOR swizzle (T2).
//  k_vtrans:  vT[bh][d][n] (bf16)
//  k_kv:      pk = exp(k.om^T - |k|^2/2)/16 ; kv += pk^T v ; pksum
//  k_kvt:     kvt[bh][j][m] bf16: rows 0..63 = kv^T, row 64 = pksum, 65..79 = 0
//  k_out:     REWRITTEN (r4): kvt staged in LDS once/block, omega in registers,
//             swapped proj mfma(om, q) -> pq^T b64 LDS writes, PV all-LDS.

typedef _Float16 half8 __attribute__((ext_vector_type(8)));
typedef short short8 __attribute__((ext_vector_type(8)));
typedef float f32x4 __attribute__((ext_vector_type(4)));
typedef unsigned short ushort4v __attribute__((ext_vector_type(4)));
typedef unsigned short ushort_t;
typedef unsigned int uint_t;

#define QKV_LD 3072

__device__ __forceinline__ ushort_t f2bf(float f) {
  uint_t u = __builtin_bit_cast(uint_t, f);
  u += 0x7fffu + ((u >> 16) & 1u);
  return (ushort_t)(u >> 16);
}

__device__ __forceinline__ void gload16(const void* g, void* l) {
  __builtin_amdgcn_global_load_lds(
      (const __attribute__((address_space(1))) void*)g,
      (__attribute__((address_space(3))) void*)l, 16, 0, 0);
}

// ---------------- W transpose+convert: wt[g][n][k] = (f16)W_g[k][n] ----------------
__global__ void k_wtrans(const float* __restrict__ Wq, const float* __restrict__ Wk,
                         const float* __restrict__ Wv, _Float16* __restrict__ wt) {
  __shared__ float t[32][33];
  const int g = blockIdx.z;
  const float* W = (g == 0) ? Wq : ((g == 1) ? Wk : Wv);
  const int n0 = blockIdx.x * 32, k0 = blockIdx.y * 32;
  const int tx = threadIdx.x, ty = threadIdx.y;
#pragma unroll
  for (int j = 0; j < 4; ++j)
    t[ty + j * 8][tx] = W[(size_t)(k0 + ty + j * 8) * 1024 + n0 + tx];
  __syncthreads();
  _Float16* o = wt + (size_t)g * 1024 * 1024;
#pragma unroll
  for (int j = 0; j < 4; ++j)
    o[(size_t)(n0 + ty + j * 8) * 1024 + k0 + tx] = (_Float16)t[tx][ty + j * 8];
}

__global__ void k_omconv(const float* __restrict__ omega, _Float16* __restrict__ om) {
  int i = blockIdx.x * 256 + threadIdx.x;
  if (i < 16384) om[i] = (_Float16)omega[i];
}

// ---------------- x convert: xh[n][k] = (f16)x[n][k] ----------------
__global__ __launch_bounds__(256) void k_xconv(const float* __restrict__ x,
                                               _Float16* __restrict__ xh) {
  size_t base = ((size_t)blockIdx.x * 256 + threadIdx.x) * 8;
  float4 f0 = *(const float4*)(x + base);
  float4 f1 = *(const float4*)(x + base + 4);
  half8 h;
  h[0] = (_Float16)f0.x; h[1] = (_Float16)f0.y; h[2] = (_Float16)f0.z; h[3] = (_Float16)f0.w;
  h[4] = (_Float16)f1.x; h[5] = (_Float16)f1.y; h[6] = (_Float16)f1.z; h[7] = (_Float16)f1.w;
  *(half8*)(xh + base) = h;
}

// ---------------- QKV GEMM: 256x256 tile, BK=32, 3-buf pipeline, counted vmcnt ----------------
__global__ __launch_bounds__(512, 2) void k_gemm(const _Float16* __restrict__ xh,
                                                 const _Float16* __restrict__ wt,
                                                 ushort_t* __restrict__ qkv) {
  __shared__ _Float16 As[3][8192];
  __shared__ _Float16 Bs[3][8192];
  const int vb = (blockIdx.x & 7) * 96 + (blockIdx.x >> 3);
  const int ct = vb % 12, rt = vb / 12;
  const int col0 = ct * 256, row0 = rt * 256;
  const int g = col0 >> 10;
  const int col0g = col0 & 1023;
  const _Float16* wtg = wt + (size_t)g * (1024 * 1024);
  const int tid = threadIdx.x;
  const int lane = tid & 63;
  const int w = tid >> 6;
  const int wm = w >> 2, wn = w & 3;
  const int l15 = lane & 15, l4 = lane >> 4;

  int srow[2], scol[2], dst[2];
#pragma unroll
  for (int i = 0; i < 2; ++i) {
    int u = i * 512 + tid;
    int rb = u >> 6, rr = (u >> 2) & 15, ccb = u & 3;
    srow[i] = rb * 16 + rr;
    scol[i] = (ccb * 8) ^ ((rr & 8) ? 16 : 0);
    dst[i] = u * 8;
  }
  const int kx = (l4 * 8) ^ ((l15 & 8) ? 16 : 0);

  auto stageA = [&](int b, int kt) {
#pragma unroll
    for (int i = 0; i < 2; ++i)
      gload16(xh + (size_t)(row0 + srow[i]) * 1024 + kt * 32 + scol[i], &As[b][dst[i]]);
  };
  auto stageB = [&](int b, int kt) {
#pragma unroll
    for (int i = 0; i < 2; ++i)
      gload16(wtg + (size_t)(col0g + srow[i]) * 1024 + kt * 32 + scol[i], &Bs[b][dst[i]]);
  };

  f32x4 acc[8][4] = {};

  stageA(0, 0); stageB(0, 0);
  stageA(1, 1); stageB(1, 1);

  int b = 0;
  for (int kt = 0; kt < 32; ++kt) {
    int b2 = b + 2; if (b2 >= 3) b2 -= 3;
    if (kt < 30) stageA(b2, kt + 2);
    if (kt < 30)       asm volatile("s_waitcnt vmcnt(6)" ::: "memory");
    else if (kt == 30) asm volatile("s_waitcnt vmcnt(4)" ::: "memory");
    else               asm volatile("s_waitcnt vmcnt(0)" ::: "memory");
    asm volatile("s_barrier" ::: "memory");

    const _Float16* Ab = &As[b][0];
    const _Float16* Bb = &Bs[b][0];
    half8 av[4], bv[4];
#pragma unroll
    for (int mi = 0; mi < 4; ++mi)
      av[mi] = *(const half8*)&Ab[(wm * 8 + mi) * 512 + l15 * 32 + kx];
#pragma unroll
    for (int ni = 0; ni < 4; ++ni)
      bv[ni] = *(const half8*)&Bb[(wn * 4 + ni) * 512 + l15 * 32 + kx];
    if (kt < 30) stageB(b2, kt + 2);
    __builtin_amdgcn_s_setprio(1);
#pragma unroll
    for (int mi = 0; mi < 4; ++mi)
#pragma unroll
      for (int ni = 0; ni < 4; ++ni)
        acc[mi][ni] = __builtin_amdgcn_mfma_f32_16x16x32_f16(av[mi], bv[ni], acc[mi][ni], 0, 0, 0);
    __builtin_amdgcn_s_setprio(0);
    asm volatile("s_barrier" ::: "memory");

    half8 av2[4];
#pragma unroll
    for (int mi = 0; mi < 4; ++mi)
      av2[mi] = *(const half8*)&Ab[(wm * 8 + 4 + mi) * 512 + l15 * 32 + kx];
    __builtin_amdgcn_s_setprio(1);
#pragma unroll
    for (int mi = 0; mi < 4; ++mi)
#pragma unroll
      for (int ni = 0; ni < 4; ++ni)
        acc[4 + mi][ni] = __builtin_amdgcn_mfma_f32_16x16x32_f16(av2[mi], bv[ni], acc[4 + mi][ni], 0, 0, 0);
    __builtin_amdgcn_s_setprio(0);

    b = b + 1; if (b == 3) b = 0;
  }

#pragma unroll
  for (int mi = 0; mi < 8; ++mi) {
    int gr0 = row0 + wm * 128 + mi * 16 + l4 * 4;
#pragma unroll
    for (int ni = 0; ni < 4; ++ni) {
      int gc = col0 + wn * 64 + ni * 16 + l15;
#pragma unroll
      for (int r = 0; r < 4; ++r) {
        float v = acc[mi][ni][r];
        ushort_t bits = (g == 2) ? f2bf(v) : __builtin_bit_cast(ushort_t, (_Float16)v);
        qkv[(size_t)(gr0 + r) * QKV_LD + gc] = bits;
      }
    }
  }
}

// ---------------- V transpose: vT[bh][d][n] = qkv_V[b n][h*64+d] ----------------
__global__ __launch_bounds__(256) void k_vtrans(const ushort_t* __restrict__ qkv,
                                                ushort_t* __restrict__ vT) {
  __shared__ ushort_t tile[64][72];
  const int bh = blockIdx.x;
  const int nc = blockIdx.y;
  const int b = bh >> 4, h = bh & 15;
  const int n0 = nc * 64;
  const int tid = threadIdx.x;
#pragma unroll
  for (int i = 0; i < 2; ++i) {
    int c = i * 256 + tid;
    int r = c >> 3, s = c & 7;
    const ushort_t* src = qkv + (size_t)(b * 4096 + n0 + r) * QKV_LD + 2048 + h * 64 + s * 8;
    *(short8*)&tile[r][s * 8] = *(const short8*)src;
  }
  __syncthreads();
#pragma unroll
  for (int i = 0; i < 2; ++i) {
    int c = i * 256 + tid;
    int d = c >> 3, s = c & 7;
    short8 v;
#pragma unroll
    for (int j = 0; j < 8; ++j) v[j] = (short)tile[s * 8 + j][d];
    *(short8*)(vT + (size_t)(bh * 64 + d) * 4096 + n0 + s * 8) = v;
  }
}

// ---------------- fused phi(k) + kv accumulation ----------------
__global__ __launch_bounds__(256) void k_kv(const ushort_t* __restrict__ qkv,
                                            const ushort_t* __restrict__ vT,
                                            const _Float16* __restrict__ om,
                                            float* __restrict__ kv,
                                            float* __restrict__ pksum) {
  __shared__ _Float16 kt[64][72];
  __shared__ ushort_t vt[64][72];
  __shared__ ushort_t pk[256][72];  // [m][n], rows 144B
  __shared__ float nrm[64];
  const int bh = blockIdx.x, split = blockIdx.y;
  const int b = bh >> 4, h = bh & 15;
  const int tid = threadIdx.x, lane = tid & 63, w = tid >> 6;
  const int l15 = lane & 15, l4 = lane >> 4;

  half8 bom[4][2];
#pragma unroll
  for (int mf = 0; mf < 4; ++mf)
#pragma unroll
    for (int ks = 0; ks < 2; ++ks)
      bom[mf][ks] = *(const half8*)(om + (size_t)(w * 64 + mf * 16 + l15) * 64 + ks * 32 + l4 * 8);

  f32x4 kvacc[4][4] = {};
  float psum[4] = {0.f, 0.f, 0.f, 0.f};

  for (int ch = 0; ch < 8; ++ch) {
    const int nbase = split * 512 + ch * 64;
#pragma unroll
    for (int i = 0; i < 2; ++i) {
      int c = i * 256 + tid;
      int r = c >> 3, s = c & 7;
      *(short8*)&kt[r][s * 8] =
          *(const short8*)(qkv + (size_t)(b * 4096 + nbase + r) * QKV_LD + 1024 + h * 64 + s * 8);
      *(short8*)&vt[r][s * 8] =
          *(const short8*)(vT + (size_t)(bh * 64 + r) * 4096 + nbase + s * 8);
    }
    __syncthreads();
    {
      int row = tid >> 2, part = tid & 3;
      float sm = 0.f;
#pragma unroll
      for (int i = 0; i < 16; ++i) {
        float kf = (float)kt[row][part * 16 + i];
        sm += kf * kf;
      }
      sm += __shfl_xor(sm, 1);
      sm += __shfl_xor(sm, 2);
      if ((tid & 3) == 0) nrm[row] = 0.5f * sm;
    }
    __syncthreads();
#pragma unroll
    for (int nf = 0; nf < 4; ++nf) {
      half8 a0 = *(const half8*)&kt[nf * 16 + l15][l4 * 8];
      half8 a1 = *(const half8*)&kt[nf * 16 + l15][32 + l4 * 8];
#pragma unroll
      for (int mf = 0; mf < 4; ++mf) {
        f32x4 f = {};
        f = __builtin_amdgcn_mfma_f32_16x16x32_f16(a0, bom[mf][0], f, 0, 0, 0);
        f = __builtin_amdgcn_mfma_f32_16x16x32_f16(a1, bom[mf][1], f, 0, 0, 0);
        ushort4v pw;
#pragma unroll
        for (int r = 0; r < 4; ++r) {
          int n = nf * 16 + l4 * 4 + r;
          float p = __expf(f[r] - nrm[n]) * 0.0625f;
          psum[mf] += p;
          pw[r] = f2bf(p);
        }
        *(ushort4v*)&pk[w * 64 + mf * 16 + l15][nf * 16 + l4 * 4] = pw;
      }
    }
    __syncthreads();
#pragma unroll
    for (int ks = 0; ks < 2; ++ks) {
      short8 pa[4];
#pragma unroll
      for (int mf = 0; mf < 4; ++mf)
        pa[mf] = *(const short8*)&pk[w * 64 + mf * 16 + l15][ks * 32 + l4 * 8];
#pragma unroll
      for (int df = 0; df < 4; ++df) {
        short8 bv = *(const short8*)&vt[df * 16 + l15][ks * 32 + l4 * 8];
#pragma unroll
        for (int mf = 0; mf < 4; ++mf)
          kvacc[mf][df] = __builtin_amdgcn_mfma_f32_16x16x32_bf16(pa[mf], bv, kvacc[mf][df], 0, 0, 0);
      }
    }
    __syncthreads();
  }
#pragma unroll
  for (int mf = 0; mf < 4; ++mf)
#pragma unroll
    for (int df = 0; df < 4; ++df)
#pragma unroll
      for (int r = 0; r < 4; ++r) {
        int m = w * 64 + mf * 16 + l4 * 4 + r;
        int d = df * 16 + l15;
        atomicAdd(&kv[((size_t)bh * 256 + m) * 64 + d], kvacc[mf][df][r]);
      }
#pragma unroll
  for (int mf = 0; mf < 4; ++mf) {
    float v = psum[mf];
    v += __shfl_xor(v, 16);
    v += __shfl_xor(v, 32);
    if (lane < 16) atomicAdd(&pksum[bh * 256 + w * 64 + mf * 16 + lane], v);
  }
}

// ---------------- kv -> kvt (B^T bf16, + pksum row 64, zero pad rows) ----------------
__global__ __launch_bounds__(256) void k_kvt(const float* __restrict__ kv,
                                             const float* __restrict__ pksum,
                                             ushort_t* __restrict__ kvt) {
  const int bh = blockIdx.x, tid = threadIdx.x;
  const int d = tid >> 2, mb = (tid & 3) * 64;
  for (int j = 0; j < 64; ++j) {
    int m = mb + j;
    kvt[((size_t)bh * 80 + d) * 256 + m] = f2bf(kv[((size_t)bh * 256 + m) * 64 + d]);
  }
  kvt[((size_t)bh * 80 + 64) * 256 + tid] = f2bf(pksum[bh * 256 + tid]);
  for (int r = 65; r < 80; ++r) kvt[((size_t)bh * 80 + r) * 256 + tid] = 0;
}

// ---------------- fused phi(q) + out (LDS-resident, reg-omega) ----------------
// grid (64 bh, 8 nsplit), 512 threads / 8 waves; 4 chunks of 128 rows.
// LDS: kvl[80][264] 42.2KB + qt[128][72] 18.4KB + pq[128][264] 67.6KB + nrm = 125.7KiB
__global__ __launch_bounds__(512) void k_out(const ushort_t* __restrict__ qkv,
                                             const ushort_t* __restrict__ kvt,
                                             const _Float16* __restrict__ om,
                                             float* __restrict__ outp) {
  __shared__ ushort_t kvl[80][264];
  __shared__ _Float16 qt[128][72];
  __shared__ ushort_t pq[128][264];  // pq^T: [n][m]
  __shared__ float nrm[128];
  const int bh = blockIdx.x, ns = blockIdx.y;
  const int b = bh >> 4, h = bh & 15;
  const int tid = threadIdx.x, lane = tid & 63, w = tid >> 6;
  const int l15 = lane & 15, l4 = lane >> 4;
  const int wn = w >> 2, wm = w & 3;  // proj: wn = n-half (64), wm = m-range (64)

  // stage kvt tile once: 80 x 256 bf16
#pragma unroll
  for (int i = 0; i < 5; ++i) {
    int u = i * 512 + tid;  // 2560 16B-chunks
    int r = u >> 5, c = (u & 31) * 8;
    *(short8*)&kvl[r][c] = *(const short8*)(kvt + ((size_t)bh * 80 + r) * 256 + c);
  }
  // loop-invariant omega fragments: wave's m-range = wm*64
  half8 bom[4][2];
#pragma unroll
  for (int mf = 0; mf < 4; ++mf)
#pragma unroll
    for (int ks = 0; ks < 2; ++ks)
      bom[mf][ks] = *(const half8*)(om + (size_t)(wm * 64 + mf * 16 + l15) * 64 + ks * 32 + l4 * 8);

  for (int ch = 0; ch < 4; ++ch) {
    const int n0 = ns * 512 + ch * 128;
    // stage q chunk: 128 x 64 fp16
#pragma unroll
    for (int i = 0; i < 2; ++i) {
      int u = i * 512 + tid;  // 1024 16B-chunks
      int r = u >> 3, s = (u & 7) * 8;
      *(half8*)&qt[r][s] =
          *(const half8*)((const _Float16*)qkv + (size_t)(b * 4096 + n0 + r) * QKV_LD + h * 64 + s);
    }
    __syncthreads();  // qt ready (also kvl on first iter); prior PV done (reads pq/kvl)
    {  // norms: 4 threads per row
      int row = tid >> 2, part = tid & 3;
      float sm = 0.f;
#pragma unroll
      for (int i = 0; i < 16; ++i) {
        float qf = (float)qt[row][part * 16 + i];
        sm += qf * qf;
      }
      sm += __shfl_xor(sm, 1);
      sm += __shfl_xor(sm, 2);
      if ((tid & 3) == 0) nrm[row] = 0.5f * sm;
    }
    __syncthreads();
    // swapped proj: D[m][n] = om . q^T ; row=m=l4*4+r, col=n=l15 -> b64 pq^T writes
#pragma unroll
    for (int nf = 0; nf < 4; ++nf) {
      half8 qa0 = *(const half8*)&qt[wn * 64 + nf * 16 + l15][l4 * 8];
      half8 qa1 = *(const half8*)&qt[wn * 64 + nf * 16 + l15][32 + l4 * 8];
      float nr = nrm[wn * 64 + nf * 16 + l15];
#pragma unroll
      for (int mf = 0; mf < 4; ++mf) {
        f32x4 f = {};
        f = __builtin_amdgcn_mfma_f32_16x16x32_f16(bom[mf][0], qa0, f, 0, 0, 0);
        f = __builtin_amdgcn_mfma_f32_16x16x32_f16(bom[mf][1], qa1, f, 0, 0, 0);
        ushort4v pw;
#pragma unroll
        for (int r = 0; r < 4; ++r) {
          float p = __expf(f[r] - nr) * 0.0625f;
          pw[r] = f2bf(p);
        }
        *(ushort4v*)&pq[wn * 64 + nf * 16 + l15][wm * 64 + mf * 16 + l4 * 4] = pw;
      }
    }
    __syncthreads();
    // PV: out[n][j] = pq . kvl^T ; wave w: n-range w*16
    f32x4 oacc[5] = {};
#pragma unroll
    for (int ks = 0; ks < 8; ++ks) {
      short8 pa = *(const short8*)&pq[w * 16 + l15][ks * 32 + l4 * 8];
#pragma unroll
      for (int cf = 0; cf < 5; ++cf) {
        short8 bv = *(const short8*)&kvl[cf * 16 + l15][ks * 32 + l4 * 8];
        oacc[cf] = __builtin_amdgcn_mfma_f32_16x16x32_bf16(pa, bv, oacc[cf], 0, 0, 0);
      }
    }
#pragma unroll
    for (int r = 0; r < 4; ++r) {
      float z = __shfl(oacc[4][r], lane & 48);  // j==64 column lives at l15==0
      float inv = 1.0f / (z + 1e-6f);
      int n = n0 + w * 16 + l4 * 4 + r;
#pragma unroll
      for (int cf = 0; cf < 4; ++cf)
        outp[(size_t)(b * 4096 + n) * 1024 + h * 64 + cf * 16 + l15] = oacc[cf][r] * inv;
    }
  }
}

extern "C" void kernel_launch(void* const* d_in, const int* in_sizes, int n_in,
                              void* d_out, int out_size, void* d_ws, size_t ws_size,
                              hipStream_t stream) {
  const float* x = (const float*)d_in[0];
  const float* Wq = (const float*)d_in[1];
  const float* Wk = (const float*)d_in[2];
  const float* Wv = (const float*)d_in[3];
  const float* omg = (const float*)d_in[4];
  float* outp = (float*)d_out;
  char* ws = (char*)d_ws;

  // ws layout (bytes), total 147,423,232 (~141 MB)
  // xh (33.5 MB) aliases vT: xh is dead after k_gemm; vT written after.
  _Float16* wt = (_Float16*)(ws);                 // 6,291,456
  _Float16* om = (_Float16*)(ws + 6291456);       //    32,768
  ushort_t* qkv = (ushort_t*)(ws + 6324224);      // 100,663,296
  _Float16* xh = (_Float16*)(ws + 106987520);     // 33,554,432 (aliases vT)
  ushort_t* vT = (ushort_t*)(ws + 106987520);     // 33,554,432
  float* kv = (float*)(ws + 140541952);           // 4,194,304
  float* pksum = (float*)(ws + 144736256);        //    65,536
  ushort_t* kvt = (ushort_t*)(ws + 144801792);    // 2,621,440

  k_wtrans<<<dim3(32, 32, 3), dim3(32, 8), 0, stream>>>(Wq, Wk, Wv, wt);
  k_omconv<<<dim3(64), dim3(256), 0, stream>>>(omg, om);
  k_xconv<<<dim3(8192), dim3(256), 0, stream>>>(x, xh);
  k_gemm<<<dim3(768), dim3(512), 0, stream>>>(xh, wt, qkv);
  k_vtrans<<<dim3(64, 64), dim3(256), 0, stream>>>(qkv, vT);
  hipMemsetAsync(kv, 0, 4194304 + 65536, stream);  // kv + pksum (contiguous)
  k_kv<<<dim3(64, 8), dim3(256), 0, stream>>>(qkv, vT, om, kv, pksum);
  k_kvt<<<dim3(64), dim3(256), 0, stream>>>(kv, pksum, kvt);
  k_out<<<dim3(64, 8), dim3(512), 0, stream>>>(qkv, kvt, om, outp);
}